// Round 1
// baseline (419.288 us; speedup 1.0000x reference)
//
#include <hip/hip_runtime.h>
#include <hip/hip_bf16.h>
#include <cstdint>
#include <cstddef>

// MFMA fragment types (per cdna_hip_programming.md §3, compile-verified on gfx950)
typedef __attribute__((ext_vector_type(8))) short short8;   // 8 bf16 in 4 VGPRs
typedef __attribute__((ext_vector_type(4))) float f32x4;    // 4 fp32 acc

// float -> bf16 bits, round-to-nearest-even (inputs are finite normals)
__device__ __forceinline__ unsigned short f2bf(float f) {
    union { float f; unsigned int u; } v;
    v.f = f;
    unsigned int r = v.u + 0x7fffu + ((v.u >> 16) & 1u);
    return (unsigned short)(r >> 16);
}

#define HPAD 72   // h-staging row stride in bf16: 144 B = 16B-aligned, 36 dwords -> worst 2-way bank alias (free)

// B-fragment swizzle for mfma_f32_16x16x32_bf16:
// fragment (ks, nt) read by lane L as 8 contiguous bf16 holds
//   B[k = ks*32 + (L>>4)*8 + j][n = nt*16 + (L&15)],  j = 0..7
// LDS element index for W[k][n]:
__device__ __forceinline__ int bswz(int k, int n) {
    const int ks = k >> 5, quad = (k >> 3) & 3, j = k & 7;
    const int nt = n >> 4, lo = n & 15;
    return ((((ks << 2) + nt) << 6) + (quad << 4) + lo) * 8 + j;
}

__global__ __launch_bounds__(256, 2)
void megnet_edge(const float* __restrict__ g_src,
                 const float* __restrict__ g_dst,
                 const float* __restrict__ g_ea,
                 const float* __restrict__ g_u,
                 const int*   __restrict__ g_batch,
                 const float* __restrict__ g_W1,
                 const float* __restrict__ g_b1,
                 const float* __restrict__ g_W2,
                 const float* __restrict__ g_b2,
                 float* __restrict__ g_out,
                 int E, int NG, int ntiles)
{
    __shared__ unsigned short w1s[256 * 64];      // 32 KB, swizzled bf16 B-fragments
    __shared__ unsigned short w2s[64 * 64];       //  8 KB
    __shared__ unsigned short hbuf[4][64 * HPAD]; // 36 KB, per-wave h staging

    const int tid = threadIdx.x;

    // ---- stage + swizzle W1 (256x64 fp32 -> bf16 fragments) ----
    for (int i = tid; i < 4096; i += 256) {             // 4096 coalesced float4 loads
        const int flat = i << 2;
        const int k = flat >> 6, n0 = flat & 63;
        const float* p = g_W1 + flat;
        #pragma unroll
        for (int c = 0; c < 4; ++c)
            w1s[bswz(k, n0 + c)] = f2bf(p[c]);
    }
    // ---- stage + swizzle W2 (64x64) ----
    for (int i = tid; i < 1024; i += 256) {
        const int flat = i << 2;
        const int k = flat >> 6, n0 = flat & 63;
        const float* p = g_W2 + flat;
        #pragma unroll
        for (int c = 0; c < 4; ++c)
            w2s[bswz(k, n0 + c)] = f2bf(p[c]);
    }
    __syncthreads();

    const int lane = tid & 63;
    const int wave = tid >> 6;
    const int lo   = lane & 15;   // A row / C col within 16-tile
    const int quad = lane >> 4;
    const short8* w1f = (const short8*)w1s;
    const short8* w2f = (const short8*)w2s;
    unsigned short* hw = &hbuf[wave][0];

    for (int tile = blockIdx.x; tile < ntiles; tile += gridDim.x) {
        const int e_base = tile * 256 + wave * 64;

        // per-(mt) row base pointers for the 4 concat segments (clamped for tail)
        const float* pseg[4][4];
        #pragma unroll
        for (int mt = 0; mt < 4; ++mt) {
            const int row = e_base + mt * 16 + lo;
            const int rc  = row < E ? row : E - 1;
            pseg[mt][0] = g_src + (size_t)rc * 64;
            pseg[mt][1] = g_dst + (size_t)rc * 64;
            pseg[mt][2] = g_ea  + (size_t)rc * 64;
            int g = g_batch[rc];
            g = g < 0 ? 0 : (g >= NG ? NG - 1 : g);
            pseg[mt][3] = g_u + (size_t)g * 64;
        }

        // ================= layer 1: [64x256] @ [256x64] per wave =================
        f32x4 acc[4][4];
        #pragma unroll
        for (int mt = 0; mt < 4; ++mt)
            #pragma unroll
            for (int nt = 0; nt < 4; ++nt)
                acc[mt][nt] = (f32x4){0.f, 0.f, 0.f, 0.f};

        #pragma unroll
        for (int ks = 0; ks < 8; ++ks) {
            const int seg = ks >> 1;                       // which concat source
            const int co  = ((ks & 1) << 5) + (quad << 3); // column offset inside segment
            short8 afrag[4];
            #pragma unroll
            for (int mt = 0; mt < 4; ++mt) {
                const float* p = pseg[mt][seg] + co;
                const float4 x = *reinterpret_cast<const float4*>(p);
                const float4 y = *reinterpret_cast<const float4*>(p + 4);
                short8 t;
                t[0] = (short)f2bf(x.x); t[1] = (short)f2bf(x.y);
                t[2] = (short)f2bf(x.z); t[3] = (short)f2bf(x.w);
                t[4] = (short)f2bf(y.x); t[5] = (short)f2bf(y.y);
                t[6] = (short)f2bf(y.z); t[7] = (short)f2bf(y.w);
                afrag[mt] = t;
            }
            #pragma unroll
            for (int nt = 0; nt < 4; ++nt) {
                const short8 b = w1f[(((ks << 2) + nt) << 6) + lane];
                #pragma unroll
                for (int mt = 0; mt < 4; ++mt)
                    acc[mt][nt] = __builtin_amdgcn_mfma_f32_16x16x32_bf16(
                        afrag[mt], b, acc[mt][nt], 0, 0, 0);
            }
        }

        // epilogue 1: +b1, relu, bf16 -> per-wave LDS (A-layout staging for layer 2)
        // C/D layout: col = nt*16+lo, row = mt*16 + quad*4 + r
        #pragma unroll
        for (int nt = 0; nt < 4; ++nt) {
            const int col = (nt << 4) + lo;
            const float bias = g_b1[col];
            #pragma unroll
            for (int mt = 0; mt < 4; ++mt) {
                #pragma unroll
                for (int r = 0; r < 4; ++r) {
                    float v = acc[mt][nt][r] + bias;
                    v = v > 0.f ? v : 0.f;
                    hw[(mt * 16 + (quad << 2) + r) * HPAD + col] = f2bf(v);
                }
            }
        }

        // ================= layer 2: [64x64] @ [64x64] per wave =================
        f32x4 acc2[4][4];
        #pragma unroll
        for (int mt = 0; mt < 4; ++mt)
            #pragma unroll
            for (int nt = 0; nt < 4; ++nt)
                acc2[mt][nt] = (f32x4){0.f, 0.f, 0.f, 0.f};

        #pragma unroll
        for (int ks = 0; ks < 2; ++ks) {
            short8 afrag[4];
            #pragma unroll
            for (int mt = 0; mt < 4; ++mt) {
                // A[m = mt*16+lo][k = ks*32 + quad*8 + j], 16B-aligned ds_read_b128
                const unsigned short* hp =
                    hw + (mt * 16 + lo) * HPAD + (ks << 5) + (quad << 3);
                afrag[mt] = *reinterpret_cast<const short8*>(hp);
            }
            #pragma unroll
            for (int nt = 0; nt < 4; ++nt) {
                const short8 b = w2f[(((ks << 2) + nt) << 6) + lane];
                #pragma unroll
                for (int mt = 0; mt < 4; ++mt)
                    acc2[mt][nt] = __builtin_amdgcn_mfma_f32_16x16x32_bf16(
                        afrag[mt], b, acc2[mt][nt], 0, 0, 0);
            }
        }

        // epilogue 2: +b2, relu, fp32 store (lanes of a quad cover 16 contiguous cols)
        #pragma unroll
        for (int mt = 0; mt < 4; ++mt) {
            #pragma unroll
            for (int r = 0; r < 4; ++r) {
                const int row = e_base + mt * 16 + (quad << 2) + r;
                if (row < E) {
                    float* op = g_out + (size_t)row * 64;
                    #pragma unroll
                    for (int nt = 0; nt < 4; ++nt) {
                        const int col = (nt << 4) + lo;
                        float v = acc2[mt][nt][r] + g_b2[col];
                        op[col] = v > 0.f ? v : 0.f;
                    }
                }
            }
        }
    }
}

extern "C" void kernel_launch(void* const* d_in, const int* in_sizes, int n_in,
                              void* d_out, int out_size, void* d_ws, size_t ws_size,
                              hipStream_t stream) {
    const float* g_src   = (const float*)d_in[0];
    const float* g_dst   = (const float*)d_in[1];
    const float* g_ea    = (const float*)d_in[2];
    const float* g_u     = (const float*)d_in[3];
    const int*   g_batch = (const int*)  d_in[4];
    const float* g_W1    = (const float*)d_in[5];
    const float* g_b1    = (const float*)d_in[6];
    const float* g_W2    = (const float*)d_in[7];
    const float* g_b2    = (const float*)d_in[8];
    float*       g_out   = (float*)d_out;

    const int E  = in_sizes[0] / 64;        // 500000
    const int NG = in_sizes[3] / 64;        // 1024
    const int ntiles = (E + 255) / 256;     // 1954

    // persistent grid: 2 blocks/CU (LDS-capped) x 256 CUs; amortizes weight staging
    int grid = ntiles < 512 ? ntiles : 512;
    megnet_edge<<<grid, 256, 0, stream>>>(g_src, g_dst, g_ea, g_u, g_batch,
                                          g_W1, g_b1, g_W2, g_b2, g_out,
                                          E, NG, ntiles);
}